// Round 1
// baseline (1399.542 us; speedup 1.0000x reference)
//
#include <hip/hip_runtime.h>
#include <math.h>

#define HEADS 4
#define CH 64
#define HC 256   // HEADS*CH

// ---------------------------------------------------------------------------
// float atomic max via int/uint ordering trick (valid for all finite floats,
// emax initialized to -inf)
__device__ __forceinline__ void atomicMaxFloat(float* addr, float val) {
    if (val >= 0.0f) {
        atomicMax((int*)addr, __float_as_int(val));
    } else {
        atomicMin((unsigned int*)addr, __float_as_uint(val));
    }
}

// ---------------------------------------------------------------------------
// Per-node feature transform: hbuf[n, 0:256] = in[n, 0:K] @ W[K,256]
// plus per-head attention logits alpha_src/alpha_dst [N,4].
// One block (256 threads) per node; wave w == head w (64 lanes == 64 channels).
__global__ void feat_kernel(const float* __restrict__ in, int K,
                            const float* __restrict__ W,
                            const float* __restrict__ a_src,
                            const float* __restrict__ a_dst,
                            float* __restrict__ hbuf,
                            float* __restrict__ asrc,
                            float* __restrict__ adst, int N) {
    __shared__ float xrow[64];
    int n = blockIdx.x;
    int t = threadIdx.x;
    if (t < K) xrow[t] = in[(size_t)n * K + t];
    __syncthreads();
    float acc = 0.f;
    for (int k = 0; k < K; ++k) acc += xrow[k] * W[k * HC + t];
    hbuf[(size_t)n * HC + t] = acc;

    int head = t >> 6;
    int lane = t & 63;
    float vs = acc * a_src[t];   // a_src flat [4][64] == index t
    float vd = acc * a_dst[t];
    for (int off = 32; off; off >>= 1) {
        vs += __shfl_down(vs, off);
        vd += __shfl_down(vd, off);
    }
    if (lane == 0) {
        asrc[n * HEADS + head] = vs;
        adst[n * HEADS + head] = vd;
    }
}

// ---------------------------------------------------------------------------
__global__ void init_emax_denom(float* __restrict__ emax,
                                float* __restrict__ denom, int n) {
    int i = blockIdx.x * blockDim.x + threadIdx.x;
    if (i < n) { emax[i] = -INFINITY; denom[i] = 0.f; }
}

__global__ void zero_kernel(float* __restrict__ p, int n) {
    int i = blockIdx.x * blockDim.x + threadIdx.x;
    if (i < n) p[i] = 0.f;
}

// ---------------------------------------------------------------------------
// Pass 1: segment max of leaky_relu(alpha_src[s]+alpha_dst[d]) over dst.
// One thread per (edge, head). Edges e >= E are self-loops (e-E, e-E).
__global__ void edge_max_kernel(const int* __restrict__ src,
                                const int* __restrict__ dst,
                                int E, int N,
                                const float* __restrict__ asrc,
                                const float* __restrict__ adst,
                                float* __restrict__ emax) {
    int idx = blockIdx.x * blockDim.x + threadIdx.x;
    int total = (E + N) * HEADS;
    if (idx >= total) return;
    int e = idx >> 2;
    int h = idx & 3;
    int s, d;
    if (e < E) { s = src[e]; d = dst[e]; } else { s = d = e - E; }
    float ev = asrc[s * HEADS + h] + adst[d * HEADS + h];
    ev = ev > 0.f ? ev : 0.2f * ev;           // leaky_relu, slope 0.2
    atomicMaxFloat(&emax[d * HEADS + h], ev);
}

// Pass 2: denom[d,h] += exp(e - emax[d,h])
__global__ void edge_sum_kernel(const int* __restrict__ src,
                                const int* __restrict__ dst,
                                int E, int N,
                                const float* __restrict__ asrc,
                                const float* __restrict__ adst,
                                const float* __restrict__ emax,
                                float* __restrict__ denom) {
    int idx = blockIdx.x * blockDim.x + threadIdx.x;
    int total = (E + N) * HEADS;
    if (idx >= total) return;
    int e = idx >> 2;
    int h = idx & 3;
    int s, d;
    if (e < E) { s = src[e]; d = dst[e]; } else { s = d = e - E; }
    float ev = asrc[s * HEADS + h] + adst[d * HEADS + h];
    ev = ev > 0.f ? ev : 0.2f * ev;
    atomicAdd(&denom[d * HEADS + h], expf(ev - emax[d * HEADS + h]));
}

// Pass 3: acc[d, c] += sum_h h[s, h, c] * alpha[e, h]
// One wave (64 lanes) per edge; lane == channel. Head-mean folded in later
// (so only 64 atomics/edge instead of 256).
__global__ void edge_agg_kernel(const int* __restrict__ src,
                                const int* __restrict__ dst,
                                int E, int N,
                                const float* __restrict__ asrc,
                                const float* __restrict__ adst,
                                const float* __restrict__ emax,
                                const float* __restrict__ denom,
                                const float* __restrict__ hbuf,
                                float* __restrict__ acc) {
    long long gid = (long long)blockIdx.x * blockDim.x + threadIdx.x;
    long long total = (long long)(E + N) * 64;
    if (gid >= total) return;
    int e = (int)(gid >> 6);
    int c = (int)(gid & 63);
    int s, d;
    if (e < E) { s = src[e]; d = dst[e]; } else { s = d = e - E; }

    float w[HEADS];
#pragma unroll
    for (int h = 0; h < HEADS; ++h) {
        float ev = asrc[s * HEADS + h] + adst[d * HEADS + h];
        ev = ev > 0.f ? ev : 0.2f * ev;
        w[h] = expf(ev - emax[d * HEADS + h]) / denom[d * HEADS + h];
    }
    float sum = 0.f;
#pragma unroll
    for (int h = 0; h < HEADS; ++h) {
        sum += hbuf[(size_t)s * HC + h * CH + c] * w[h];
    }
    atomicAdd(&acc[(size_t)d * CH + c], sum);
}

// ---------------------------------------------------------------------------
// out[n,c] = elu(acc[n,c]/HEADS + b[c]) (+ residual[n,c])
__global__ void postproc_kernel(float* __restrict__ acc,
                                const float* __restrict__ b,
                                const float* __restrict__ residual,
                                int N) {
    int i = blockIdx.x * blockDim.x + threadIdx.x;
    if (i >= N * CH) return;
    int c = i & 63;
    float v = acc[i] * (1.0f / HEADS) + b[c];
    v = v > 0.f ? v : expm1f(v);              // elu, alpha=1
    if (residual) v += residual[i];
    acc[i] = v;
}

// ---------------------------------------------------------------------------
// out[n] = h3[n,:] . lin_w + lin_b ; wave per node
__global__ void final_kernel(const float* __restrict__ h3,
                             const float* __restrict__ lin_w,
                             const float* __restrict__ lin_b,
                             float* __restrict__ out, int N) {
    long long gid = (long long)blockIdx.x * blockDim.x + threadIdx.x;
    if (gid >= (long long)N * 64) return;
    int n = (int)(gid >> 6);
    int lane = (int)(gid & 63);
    float v = h3[(size_t)n * CH + lane] * lin_w[lane];
    for (int off = 32; off; off >>= 1) v += __shfl_down(v, off);
    if (lane == 0) out[n] = v + lin_b[0];
}

// ---------------------------------------------------------------------------
extern "C" void kernel_launch(void* const* d_in, const int* in_sizes, int n_in,
                              void* d_out, int out_size, void* d_ws, size_t ws_size,
                              hipStream_t stream) {
    const float* x      = (const float*)d_in[0];
    const int*   ei     = (const int*)  d_in[1];
    const float* W1     = (const float*)d_in[2];
    const float* a1s    = (const float*)d_in[3];
    const float* a1d    = (const float*)d_in[4];
    const float* b1     = (const float*)d_in[5];
    const float* W2     = (const float*)d_in[6];
    const float* a2s    = (const float*)d_in[7];
    const float* a2d    = (const float*)d_in[8];
    const float* b2     = (const float*)d_in[9];
    const float* W3     = (const float*)d_in[10];
    const float* a3s    = (const float*)d_in[11];
    const float* a3d    = (const float*)d_in[12];
    const float* b3     = (const float*)d_in[13];
    const float* lin_w  = (const float*)d_in[14];
    const float* lin_b  = (const float*)d_in[15];

    const int N = in_sizes[0] / 3;
    const int E = in_sizes[1] / 2;
    const int Et = E + N;
    const int* src = ei;       // edge_index[0]
    const int* dst = ei + E;   // edge_index[1]

    float* ws    = (float*)d_ws;
    float* hbuf  = ws;                              // N*256
    float* asrc  = hbuf  + (size_t)N * HC;          // N*4
    float* adst  = asrc  + (size_t)N * HEADS;       // N*4
    float* emax  = adst  + (size_t)N * HEADS;       // N*4
    float* denom = emax  + (size_t)N * HEADS;       // N*4
    float* bufA  = denom + (size_t)N * HEADS;       // N*64 (h1)
    float* bufB  = bufA  + (size_t)N * CH;          // N*64 (h2)
    float* bufC  = bufB  + (size_t)N * CH;          // N*64 (h3)

    const int B = 256;
    auto run_layer = [&](const float* inp, int K, const float* W,
                         const float* as, const float* ad, const float* bb,
                         const float* residual, float* outbuf) {
        feat_kernel<<<N, B, 0, stream>>>(inp, K, W, as, ad, hbuf, asrc, adst, N);
        init_emax_denom<<<(N * HEADS + B - 1) / B, B, 0, stream>>>(emax, denom, N * HEADS);
        zero_kernel<<<(N * CH + B - 1) / B, B, 0, stream>>>(outbuf, N * CH);
        int eh_blocks = (Et * HEADS + B - 1) / B;
        edge_max_kernel<<<eh_blocks, B, 0, stream>>>(src, dst, E, N, asrc, adst, emax);
        edge_sum_kernel<<<eh_blocks, B, 0, stream>>>(src, dst, E, N, asrc, adst, emax, denom);
        long long agg_threads = (long long)Et * 64;
        int agg_blocks = (int)((agg_threads + B - 1) / B);
        edge_agg_kernel<<<agg_blocks, B, 0, stream>>>(src, dst, E, N, asrc, adst,
                                                      emax, denom, hbuf, outbuf);
        postproc_kernel<<<(N * CH + B - 1) / B, B, 0, stream>>>(outbuf, bb, residual, N);
    };

    run_layer(x,    3,  W1, a1s, a1d, b1, nullptr, bufA);  // h1
    run_layer(bufA, 64, W2, a2s, a2d, b2, bufA,    bufB);  // h2 = elu(...) + h1
    run_layer(bufB, 64, W3, a3s, a3d, b3, bufB,    bufC);  // h3 = elu(...) + h2

    long long fin_threads = (long long)N * 64;
    final_kernel<<<(int)((fin_threads + B - 1) / B), B, 0, stream>>>(
        bufC, lin_w, lin_b, (float*)d_out, N);
}